// Round 4
// baseline (240.103 us; speedup 1.0000x reference)
//
#include <hip/hip_runtime.h>

// Problem constants (fixed by reference setup_inputs).
#define N 32
#define T 64
#define C 256
#define L 64

// ---------------------------------------------------------------------------
// Kernel 1: partial[t][n][l] = sum_c q[n,t,c,l] * k[t,n,c]
// Grid (T, N) = 2048 blocks x 256 threads (8 blocks/CU, 32 waves/CU).
// Latency fix: ALL 16 float4 q-loads issued back-to-back into a register
// array before any consumption -> 16 loads in flight per wave
// (16 x 16 B x 32 waves = 8 KB/CU, ~ the HBM bandwidth-delay product).
// k-row staged in LDS concurrently (loads don't depend on it).
// ---------------------------------------------------------------------------
__global__ __launch_bounds__(256, 8) void scores_partial_kernel(
    const float* __restrict__ q, const float* __restrict__ k,
    float* __restrict__ partial) {
  const int t    = blockIdx.x;
  const int n    = blockIdx.y;
  const int tid  = threadIdx.x;
  const int lane = tid & 63;
  const int wave = tid >> 6;      // 0..3
  const int sub  = lane >> 4;     // quarter-wave within wave
  const int lq   = lane & 15;     // lane within quarter-wave -> l-group
  const int g    = wave * 4 + sub; // group id 0..15 -> c residue

  __shared__ float sk[C];         // k row for this (t,n): 1 KiB
  __shared__ float sred[4 * L];   // cross-wave reduction: 1 KiB

  const float* __restrict__ qrow = q + ((size_t)(n * T + t) * C) * L + lq * 4;

  // Issue all 16 coalesced loads first (each wave instruction covers 1 KiB).
  float4 qv[16];
  #pragma unroll
  for (int i = 0; i < 16; ++i)
    qv[i] = *reinterpret_cast<const float4*>(qrow + (size_t)(g + 16 * i) * L);

  // k staging overlaps the global-load latency.
  sk[tid] = k[(t * N + n) * C + tid];   // tid == c, coalesced
  __syncthreads();

  float4 acc = make_float4(0.f, 0.f, 0.f, 0.f);
  #pragma unroll
  for (int i = 0; i < 16; ++i) {
    const float kv = sk[g + 16 * i];    // LDS broadcast within quarter-wave
    acc.x = fmaf(qv[i].x, kv, acc.x);
    acc.y = fmaf(qv[i].y, kv, acc.y);
    acc.z = fmaf(qv[i].z, kv, acc.z);
    acc.w = fmaf(qv[i].w, kv, acc.w);
  }

  // Sum the 4 quarter-waves of this wave (same l-groups, different c's).
  acc.x += __shfl_xor(acc.x, 16); acc.y += __shfl_xor(acc.y, 16);
  acc.z += __shfl_xor(acc.z, 16); acc.w += __shfl_xor(acc.w, 16);
  acc.x += __shfl_xor(acc.x, 32); acc.y += __shfl_xor(acc.y, 32);
  acc.z += __shfl_xor(acc.z, 32); acc.w += __shfl_xor(acc.w, 32);

  // Cross-wave reduction via LDS.
  if (lane < 16) {
    sred[wave * L + lq * 4 + 0] = acc.x;
    sred[wave * L + lq * 4 + 1] = acc.y;
    sred[wave * L + lq * 4 + 2] = acc.z;
    sred[wave * L + lq * 4 + 3] = acc.w;
  }
  __syncthreads();
  if (tid < L) {
    const float s = sred[tid] + sred[L + tid] + sred[2 * L + tid] + sred[3 * L + tid];
    partial[(size_t)t * (N * L) + n * L + tid] = s;  // deterministic, no atomics
  }
}

// ---------------------------------------------------------------------------
// Kernel 2: softmax prologue + out[t,n,c] = dot(q[n,t,c,:], probs[n,:]).
// Thread tid == c owns one output element (no cross-lane ops at all).
// Latency fix: the 16 q-loads (256 B/thread, L3-resident after K1) are
// issued BEFORE the softmax prologue — they don't depend on probs, so their
// entire latency hides under the partial-reduce + softmax.
// ---------------------------------------------------------------------------
__global__ __launch_bounds__(256, 8) void out_kernel(
    const float* __restrict__ q, const float* __restrict__ partial,
    float* __restrict__ out) {
  const int t    = blockIdx.x;
  const int n    = blockIdx.y;
  const int tid  = threadIdx.x;
  const int lane = tid & 63;
  const int wave = tid >> 6;

  __shared__ float sred[4 * L];
  __shared__ __align__(16) float probs[L];

  // Issue-early: 16 independent float4 loads into registers.
  const float* __restrict__ qrow = q + ((size_t)((n * T + t) * C + tid)) * L;
  float4 qv[16];
  #pragma unroll
  for (int i = 0; i < 16; ++i)
    qv[i] = *reinterpret_cast<const float4*>(qrow + i * 4);

  // Softmax prologue (overlaps the q-load latency).
  {
    float s = 0.f;
    #pragma unroll 4
    for (int b = wave * 16; b < wave * 16 + 16; ++b)
      s += partial[(size_t)b * (N * L) + n * L + lane];  // coalesced 256 B
    sred[wave * L + lane] = s;
  }
  __syncthreads();
  if (tid < L) {
    float v = sred[tid] + sred[L + tid] + sred[2 * L + tid] + sred[3 * L + tid];
    float m = v;
    #pragma unroll
    for (int off = 32; off > 0; off >>= 1) m = fmaxf(m, __shfl_xor(m, off));
    const float e = __expf(v - m);
    float z = e;
    #pragma unroll
    for (int off = 32; off > 0; off >>= 1) z += __shfl_xor(z, off);
    probs[tid] = e / z;
  }
  __syncthreads();

  float d = 0.f;
  #pragma unroll
  for (int i = 0; i < 16; ++i) {
    const float4 pv = *reinterpret_cast<const float4*>(&probs[i * 4]);  // LDS broadcast
    d += qv[i].x * pv.x + qv[i].y * pv.y + qv[i].z * pv.z + qv[i].w * pv.w;
  }
  out[(size_t)(t * N + n) * C + tid] = d;   // coalesced 1 KiB per block
}

extern "C" void kernel_launch(void* const* d_in, const int* in_sizes, int n_in,
                              void* d_out, int out_size, void* d_ws, size_t ws_size,
                              hipStream_t stream) {
  const float* q = (const float*)d_in[0];   // query: (32,64,256,64) fp32
  const float* k = (const float*)d_in[1];   // key:   (64,32,256)    fp32
  float* out = (float*)d_out;               // out:   (64,32,256)    fp32
  float* partial = (float*)d_ws;            // [64][32][64] fp32 = 512 KiB scratch

  dim3 grid(T, N);                          // 2048 blocks x 256 threads
  scores_partial_kernel<<<grid, 256, 0, stream>>>(q, k, partial);
  out_kernel<<<grid, 256, 0, stream>>>(q, partial, out);
}